// Round 4
// baseline (237.078 us; speedup 1.0000x reference)
//
#include <hip/hip_runtime.h>
#include <hip/hip_bf16.h>

typedef __bf16 bf16_t;
typedef __bf16 bf16x8 __attribute__((ext_vector_type(8)));
typedef __bf16 bf16x4 __attribute__((ext_vector_type(4)));
typedef float floatx4 __attribute__((ext_vector_type(4)));
typedef short short4v __attribute__((ext_vector_type(4)));

#define D_MODEL 1024
#define SEQ     2048
#define BATCH   2
#define NHEAD   16
#define HDIM    64
#define MTOT    (BATCH * SEQ)   /* 4096 */
#define LROWS   (32 * 2048)     /* q-rows across all (b,h) */
#define OPS     (32 * 64 * 2048) /* Opart split stride (floats) */

// 1/sqrt(64) * log2(e): exp2f(s) == exp(s/8) with this folded into Q
#define QSCALE  0.18033688011112042f

union PBu { bf16x4 b; short4v s; };

__device__ __forceinline__ void async_copy16(const bf16_t* g, bf16_t* l) {
    __builtin_amdgcn_global_load_lds(
        (const __attribute__((address_space(1))) void*)g,
        (__attribute__((address_space(3))) void*)l, 16, 0, 0);
}

// ---------------- convert fp32 -> bf16 (x) ----------------
__global__ void cvt_f32_bf16(const float* __restrict__ x, bf16_t* __restrict__ y, int n) {
    int i = (blockIdx.x * 256 + threadIdx.x) * 4;
    if (i < n) {
        const float4 v = *(const float4*)(x + i);
        bf16x4 o = { (bf16_t)v.x, (bf16_t)v.y, (bf16_t)v.z, (bf16_t)v.w };
        *(bf16x4*)(y + i) = o;
    }
}

// ---------------- transpose 4x W [K,N] f32 -> Wt [N,K] bf16 ----------------
__global__ void transpose_w4(
    const float* __restrict__ W0, const float* __restrict__ W1,
    const float* __restrict__ W2, const float* __restrict__ W3,
    bf16_t* __restrict__ T0, bf16_t* __restrict__ T1,
    bf16_t* __restrict__ T2, bf16_t* __restrict__ T3)
{
    __shared__ float tile[32][33];
    const int z = blockIdx.z;
    const float* W = (z == 0) ? W0 : (z == 1) ? W1 : (z == 2) ? W2 : W3;
    bf16_t*     Wt = (z == 0) ? T0 : (z == 1) ? T1 : (z == 2) ? T2 : T3;
    const int tx = threadIdx.x, ty = threadIdx.y;
    const int k0 = blockIdx.y * 32, n0 = blockIdx.x * 32;
#pragma unroll
    for (int j = 0; j < 32; j += 8)
        tile[ty + j][tx] = W[(size_t)(k0 + ty + j) * D_MODEL + n0 + tx];
    __syncthreads();
#pragma unroll
    for (int j = 0; j < 32; j += 8)
        Wt[(size_t)(n0 + ty + j) * D_MODEL + k0 + tx] = (bf16_t)tile[tx][ty + j];
}

// ---------------- 128x128 GEMM mainloop (global_load_lds + XOR swizzle) ----------------
__device__ __forceinline__ void gemm_mainloop(
    const bf16_t* __restrict__ A, const bf16_t* __restrict__ Bt,
    int m0, int n0, bf16_t* As, bf16_t* Bs, floatx4 acc[4][4])
{
    const int tid  = threadIdx.x;
    const int lane = tid & 63;
    const int wid  = tid >> 6;
    const int quad = lane >> 4;
    const int col  = lane & 15;
    const int wm   = (wid >> 1) * 64;
    const int wn   = (wid & 1) * 64;
    const int srow = tid >> 3;                       // 0..31
    const int scc  = ((tid & 7) ^ (srow & 7)) * 8;   // swizzled source col chunk
    const int xorc = col & 7;

    const bf16_t* Ag = A  + (size_t)(m0 + srow) * D_MODEL + scc;
    const bf16_t* Bg = Bt + (size_t)(n0 + srow) * D_MODEL + scc;
    bf16_t* Al = As + tid * 8;
    bf16_t* Bl = Bs + tid * 8;

    for (int kb = 0; kb < D_MODEL; kb += 64) {
#pragma unroll
        for (int p = 0; p < 4; ++p) {
            async_copy16(Ag + kb + p * (32 * D_MODEL), Al + p * 2048);
            async_copy16(Bg + kb + p * (32 * D_MODEL), Bl + p * 2048);
        }
        __syncthreads();
#pragma unroll
        for (int kh = 0; kh < 2; ++kh) {
            bf16x8 af[4], bfr[4];
#pragma unroll
            for (int i = 0; i < 4; ++i)
                af[i] = *(const bf16x8*)(As + (wm + i * 16 + col) * 64 + (((kh * 4 + quad) ^ xorc) * 8));
#pragma unroll
            for (int j = 0; j < 4; ++j)
                bfr[j] = *(const bf16x8*)(Bs + (wn + j * 16 + col) * 64 + (((kh * 4 + quad) ^ xorc) * 8));
#pragma unroll
            for (int i = 0; i < 4; ++i)
#pragma unroll
                for (int j = 0; j < 4; ++j)
                    acc[i][j] = __builtin_amdgcn_mfma_f32_16x16x32_bf16(af[i], bfr[j], acc[i][j], 0, 0, 0);
        }
        __syncthreads();
    }
}

// ---------------- QKV GEMM: grid (8, 32, 3) ----------------
__global__ __launch_bounds__(256, 3) void gemm_qkv(
    const bf16_t* __restrict__ xb,
    const bf16_t* __restrict__ Wtq, const bf16_t* __restrict__ Wtk, const bf16_t* __restrict__ Wtv,
    const float* __restrict__ bq, const float* __restrict__ bk, const float* __restrict__ bv,
    bf16_t* __restrict__ Q, bf16_t* __restrict__ Kh, bf16_t* __restrict__ Vt)
{
    __shared__ bf16_t As[128 * 64];
    __shared__ bf16_t Bs[128 * 64];
    const int z = blockIdx.z;
    const bf16_t* Bt   = (z == 0) ? Wtq : (z == 1) ? Wtk : Wtv;
    const float*  bias = (z == 0) ? bq  : (z == 1) ? bk  : bv;
    bf16_t*       O    = (z == 0) ? Q   : (z == 1) ? Kh  : Vt;
    const float   qs   = (z == 0) ? QSCALE : 1.0f;
    const int m0 = blockIdx.y * 128;
    const int n0 = blockIdx.x * 128;

    floatx4 acc[4][4];
#pragma unroll
    for (int i = 0; i < 4; ++i)
#pragma unroll
        for (int j = 0; j < 4; ++j)
            acc[i][j] = (floatx4){0.f, 0.f, 0.f, 0.f};

    gemm_mainloop(xb, Bt, m0, n0, As, Bs, acc);

    const int tid  = threadIdx.x;
    const int lane = tid & 63;
    const int wid  = tid >> 6;
    const int quad = lane >> 4;
    const int col  = lane & 15;
    const int wm   = (wid >> 1) * 64;
    const int wn   = (wid & 1) * 64;

    if (z == 2) {
        // Vt[b,h,d,s]: 4 consecutive s per lane -> bf16x4 stores
#pragma unroll
        for (int i = 0; i < 4; ++i) {
#pragma unroll
            for (int j = 0; j < 4; ++j) {
                const int n = n0 + wn + j * 16 + col;
                const float bb = bias[n];
                const int mb = m0 + wm + i * 16 + quad * 4;
                const size_t bhb = (size_t)((mb >> 11) * NHEAD + (n >> 6)) * (SEQ * HDIM);
                bf16x4 pk = { (bf16_t)(acc[i][j][0] + bb), (bf16_t)(acc[i][j][1] + bb),
                              (bf16_t)(acc[i][j][2] + bb), (bf16_t)(acc[i][j][3] + bb) };
                *(bf16x4*)(O + bhb + (size_t)(n & 63) * SEQ + (mb & 2047)) = pk;
            }
        }
    } else {
#pragma unroll
        for (int i = 0; i < 4; ++i) {
#pragma unroll
            for (int j = 0; j < 4; ++j) {
                const int n = n0 + wn + j * 16 + col;
                const float bb = bias[n];
#pragma unroll
                for (int r = 0; r < 4; ++r) {
                    const int m = m0 + wm + i * 16 + quad * 4 + r;
                    const float v = (acc[i][j][r] + bb) * qs;
                    const size_t bhb = (size_t)((m >> 11) * NHEAD + (n >> 6)) * (SEQ * HDIM);
                    O[bhb + (size_t)(m & 2047) * HDIM + (n & 63)] = (bf16_t)v;
                }
            }
        }
    }
}

// ---------------- flash attention, S^T formulation, K-split x2, KT=128 ----------------
// grid (S/128=16, B*H=32, 2 splits), 256 thr; wave owns 32 q rows (2 strips of 16)
__global__ __launch_bounds__(256, 4) void attn_kernel(
    const bf16_t* __restrict__ Q, const bf16_t* __restrict__ K,
    const bf16_t* __restrict__ Vt, float* __restrict__ Opart, float* __restrict__ lpart)
{
    __shared__ bf16_t Ks[128 * 64];   // [kk][d], swizzled (16 KB)
    __shared__ bf16_t Vs[64 * 128];   // [d][s_local], swizzled (16 KB)

    const int tid  = threadIdx.x;
    const int lane = tid & 63;
    const int wid  = tid >> 6;
    const int quad = lane >> 4;
    const int col  = lane & 15;
    const int xorc = col & 7;
    const int bh   = blockIdx.y;
    const int sp   = blockIdx.z;
    const int q0   = blockIdx.x * 128;

    const bf16_t* Qb = Q  + (size_t)bh * (SEQ * HDIM);
    const bf16_t* Kb = K  + (size_t)bh * (SEQ * HDIM);
    const bf16_t* Vb = Vt + (size_t)bh * (SEQ * HDIM);  // [d][s]

    // Q B-fragments (n=q=col, kk=d=quad*8+j); scale folded in
    bf16x8 qf[2][2];
#pragma unroll
    for (int st = 0; st < 2; ++st) {
        const int qrow = q0 + wid * 32 + st * 16 + col;
        qf[st][0] = *(const bf16x8*)(Qb + (size_t)qrow * HDIM + quad * 8);
        qf[st][1] = *(const bf16x8*)(Qb + (size_t)qrow * HDIM + 32 + quad * 8);
    }

    floatx4 o_acc[2][4];   // O^T: lane holds (d = dt*16+quad*4+r, q = col)
    float lsum[2] = {0.f, 0.f};
#pragma unroll
    for (int st = 0; st < 2; ++st)
#pragma unroll
        for (int dt = 0; dt < 4; ++dt)
            o_acc[st][dt] = (floatx4){0.f, 0.f, 0.f, 0.f};

    // staging maps (async copy: LDS dest = tid*16B per 4KB chunk)
    const int krow = tid >> 3;                          // 0..31
    const int sccK = ((tid & 7) ^ (krow & 7)) * 8;
    const int vrow = tid >> 4;                          // 0..15
    const int sccV = ((tid & 15) ^ (vrow & 7)) * 8;
    const bf16_t* Kg = Kb + (size_t)(sp * 1024 + krow) * HDIM + sccK;
    const bf16_t* Vg = Vb + (size_t)vrow * SEQ + sp * 1024 + sccV;
    bf16_t* KsL = Ks + tid * 8;
    bf16_t* VsL = Vs + tid * 8;

    for (int it = 0; it < 8; ++it) {
        const int ko = it * 128;
#pragma unroll
        for (int p = 0; p < 4; ++p) {
            async_copy16(Kg + (size_t)(ko + p * 32) * HDIM, KsL + p * 2048);
            async_copy16(Vg + ko + (size_t)(p * 16) * SEQ, VsL + p * 2048);
        }
        __syncthreads();

#pragma unroll
        for (int kh = 0; kh < 2; ++kh) {
            // K fragments (A-operand of S^T): m = k = kh*64+t*16+col, kk = d
            bf16x8 kf[4][2];
#pragma unroll
            for (int t = 0; t < 4; ++t) {
                kf[t][0] = *(const bf16x8*)(Ks + (kh * 64 + t * 16 + col) * 64 + ((quad ^ xorc) * 8));
                kf[t][1] = *(const bf16x8*)(Ks + (kh * 64 + t * 16 + col) * 64 + (((4 + quad) ^ xorc) * 8));
            }
            // V^T fragments (A-operand of PV, K=16): m = d = dt*16+col, k = kh*64+t*16+quad*4+j
            short4v vfr[4][4];
#pragma unroll
            for (int dt = 0; dt < 4; ++dt)
#pragma unroll
                for (int t = 0; t < 4; ++t) {
                    const int sch = kh * 8 + t * 2 + (quad >> 1);
                    vfr[dt][t] = *(const short4v*)(Vs + (dt * 16 + col) * 128 + ((sch ^ xorc) * 8) + (quad & 1) * 4);
                }

#pragma unroll
            for (int st = 0; st < 2; ++st) {
                floatx4 s_acc[4];
                short4v pb[4];
#pragma unroll
                for (int t = 0; t < 4; ++t) {
                    s_acc[t] = (floatx4){0.f, 0.f, 0.f, 0.f};
                    s_acc[t] = __builtin_amdgcn_mfma_f32_16x16x32_bf16(kf[t][0], qf[st][0], s_acc[t], 0, 0, 0);
                    s_acc[t] = __builtin_amdgcn_mfma_f32_16x16x32_bf16(kf[t][1], qf[st][1], s_acc[t], 0, 0, 0);
                }
#pragma unroll
                for (int t = 0; t < 4; ++t) {
                    const float p0 = exp2f(s_acc[t][0]);
                    const float p1 = exp2f(s_acc[t][1]);
                    const float p2 = exp2f(s_acc[t][2]);
                    const float p3 = exp2f(s_acc[t][3]);
                    lsum[st] += (p0 + p1) + (p2 + p3);
                    PBu u;
                    u.b = (bf16x4){ (bf16_t)p0, (bf16_t)p1, (bf16_t)p2, (bf16_t)p3 };
                    pb[t] = u.s;
                }
#pragma unroll
                for (int dt = 0; dt < 4; ++dt)
#pragma unroll
                    for (int t = 0; t < 4; ++t)
                        o_acc[st][dt] = __builtin_amdgcn_mfma_f32_16x16x16bf16_1k(vfr[dt][t], pb[t], o_acc[st][dt], 0, 0, 0);
            }
        }
        __syncthreads();
    }

    // l: lanes hold disjoint k-partials (by quad); reduce across quads
#pragma unroll
    for (int st = 0; st < 2; ++st) {
        lsum[st] += __shfl_xor(lsum[st], 16, 64);
        lsum[st] += __shfl_xor(lsum[st], 32, 64);
    }

    // store fp32 partials: Opart[sp][bh][d][q], lpart[sp][bh*2048+q]
    const size_t osp = (size_t)sp * OPS + (size_t)bh * 64 * 2048;
#pragma unroll
    for (int st = 0; st < 2; ++st) {
        const int q = q0 + wid * 32 + st * 16 + col;
#pragma unroll
        for (int dt = 0; dt < 4; ++dt)
#pragma unroll
            for (int r = 0; r < 4; ++r) {
                const int d = dt * 16 + quad * 4 + r;
                Opart[osp + (size_t)d * 2048 + q] = o_acc[st][dt][r];
            }
        if (lane < 16)
            lpart[(size_t)sp * LROWS + (size_t)bh * 2048 + q0 + wid * 32 + st * 16 + lane] = lsum[st];
    }
}

// ---------------- combine splits + transpose O^T -> A2 [b,s,h*64+d] bf16 ----------------
__global__ __launch_bounds__(256) void attn_combine(
    const float* __restrict__ Op, const float* __restrict__ lp, bf16_t* __restrict__ A2)
{
    __shared__ float Linv[64];
    __shared__ bf16_t T[64 * 72];    // [q_local][d] padded
    const int tid = threadIdx.x;
    const int qb  = blockIdx.x * 64;
    const int bh  = blockIdx.y;
    const int b   = bh >> 4, h = bh & 15;

    if (tid < 64)
        Linv[tid] = 1.0f / (lp[(size_t)bh * 2048 + qb + tid] + lp[LROWS + (size_t)bh * 2048 + qb + tid]);
    __syncthreads();

    const int d  = tid >> 2;
    const int qo = (tid & 3) * 16;
    const size_t base = ((size_t)bh * 64 + d) * 2048 + qb + qo;
#pragma unroll
    for (int i = 0; i < 16; i += 4) {
        const float4 a = *(const float4*)(Op + base + i);
        const float4 c = *(const float4*)(Op + OPS + base + i);
        T[(qo + i + 0) * 72 + d] = (bf16_t)((a.x + c.x) * Linv[qo + i + 0]);
        T[(qo + i + 1) * 72 + d] = (bf16_t)((a.y + c.y) * Linv[qo + i + 1]);
        T[(qo + i + 2) * 72 + d] = (bf16_t)((a.z + c.z) * Linv[qo + i + 2]);
        T[(qo + i + 3) * 72 + d] = (bf16_t)((a.w + c.w) * Linv[qo + i + 3]);
    }
    __syncthreads();

    const int q  = tid >> 2;
    const int dd = (tid & 3) * 16;
    const bf16x8 o0 = *(const bf16x8*)(T + q * 72 + dd);
    const bf16x8 o1 = *(const bf16x8*)(T + q * 72 + dd + 8);
    bf16_t* dst = A2 + ((size_t)(b * 2048 + qb + q)) * D_MODEL + h * 64 + dd;
    *(bf16x8*)(dst) = o0;
    *(bf16x8*)(dst + 8) = o1;
}

// ---------------- output projection: 64x128 tiles, grid (8, 64) ----------------
__global__ __launch_bounds__(256, 3) void gemm_proj(
    const bf16_t* __restrict__ A2, const bf16_t* __restrict__ Wto,
    const float* __restrict__ bo, float* __restrict__ out)
{
    __shared__ bf16_t As[64 * 64];    // 8 KB
    __shared__ bf16_t Bs[128 * 64];   // 16 KB
    const int m0 = blockIdx.y * 64;
    const int n0 = blockIdx.x * 128;

    const int tid  = threadIdx.x;
    const int lane = tid & 63;
    const int wid  = tid >> 6;
    const int quad = lane >> 4;
    const int col  = lane & 15;
    const int wm   = (wid >> 1) * 32;
    const int wn   = (wid & 1) * 64;
    const int srow = tid >> 3;
    const int scc  = ((tid & 7) ^ (srow & 7)) * 8;
    const int xorc = col & 7;

    floatx4 acc[2][4];
#pragma unroll
    for (int i = 0; i < 2; ++i)
#pragma unroll
        for (int j = 0; j < 4; ++j)
            acc[i][j] = (floatx4){0.f, 0.f, 0.f, 0.f};

    const bf16_t* Ag = A2  + (size_t)(m0 + srow) * D_MODEL + scc;
    const bf16_t* Bg = Wto + (size_t)(n0 + srow) * D_MODEL + scc;
    bf16_t* Al = As + tid * 8;
    bf16_t* Bl = Bs + tid * 8;

    for (int kb = 0; kb < D_MODEL; kb += 64) {
#pragma unroll
        for (int p = 0; p < 2; ++p)
            async_copy16(Ag + kb + p * (32 * D_MODEL), Al + p * 2048);
#pragma unroll
        for (int p = 0; p < 4; ++p)
            async_copy16(Bg + kb + p * (32 * D_MODEL), Bl + p * 2048);
        __syncthreads();
#pragma unroll
        for (int kh = 0; kh < 2; ++kh) {
            bf16x8 af[2], bfr[4];
#pragma unroll
            for (int i = 0; i < 2; ++i)
                af[i] = *(const bf16x8*)(As + (wm + i * 16 + col) * 64 + (((kh * 4 + quad) ^ xorc) * 8));
#pragma unroll
            for (int j = 0; j < 4; ++j)
                bfr[j] = *(const bf16x8*)(Bs + (wn + j * 16 + col) * 64 + (((kh * 4 + quad) ^ xorc) * 8));
#pragma unroll
            for (int i = 0; i < 2; ++i)
#pragma unroll
                for (int j = 0; j < 4; ++j)
                    acc[i][j] = __builtin_amdgcn_mfma_f32_16x16x32_bf16(af[i], bfr[j], acc[i][j], 0, 0, 0);
        }
        __syncthreads();
    }

#pragma unroll
    for (int i = 0; i < 2; ++i) {
#pragma unroll
        for (int j = 0; j < 4; ++j) {
            const int n = n0 + wn + j * 16 + col;
            const float bb = bo[n];
#pragma unroll
            for (int r = 0; r < 4; ++r) {
                const int m = m0 + wm + i * 16 + quad * 4 + r;
                out[(size_t)m * D_MODEL + n] = acc[i][j][r] + bb;
            }
        }
    }
}

// ---------------- host ----------------
extern "C" void kernel_launch(void* const* d_in, const int* in_sizes, int n_in,
                              void* d_out, int out_size, void* d_ws, size_t ws_size,
                              hipStream_t stream) {
    const float* x  = (const float*)d_in[0];
    const float* Wq = (const float*)d_in[1];
    const float* bq = (const float*)d_in[2];
    const float* Wk = (const float*)d_in[3];
    const float* bk = (const float*)d_in[4];
    const float* Wv = (const float*)d_in[5];
    const float* bv = (const float*)d_in[6];
    const float* Wo = (const float*)d_in[7];
    const float* bo = (const float*)d_in[8];
    float* out = (float*)d_out;

    const size_t MB = 1ull << 20;
    char* ws = (char*)d_ws;
    bf16_t* Q     = (bf16_t*)(ws + 0 * MB);    // 8 MB  [b,h,s,d]
    bf16_t* Kh    = (bf16_t*)(ws + 8 * MB);    // 8 MB  [b,h,s,d]
    bf16_t* Vt    = (bf16_t*)(ws + 16 * MB);   // 8 MB  [b,h,d,s]
    bf16_t* A2    = (bf16_t*)(ws + 24 * MB);   // 8 MB  [b,s,h*d]
    bf16_t* xb    = (bf16_t*)(ws + 32 * MB);   // 8 MB (dead after gemm_qkv)
    float*  lpart = (float*)(ws + 32 * MB);    // 0.5 MB, overlays xb (attn runs after)
    bf16_t* Wtq   = (bf16_t*)(ws + 40 * MB);   // 2 MB each
    bf16_t* Wtk   = (bf16_t*)(ws + 42 * MB);
    bf16_t* Wtv   = (bf16_t*)(ws + 44 * MB);
    bf16_t* Wto   = (bf16_t*)(ws + 46 * MB);
    float*  Opart = (float*)(ws + 48 * MB);    // 32 MB (2 splits x 16 MB)

    const int nx = MTOT * D_MODEL;
    cvt_f32_bf16<<<nx / (256 * 4), 256, 0, stream>>>(x, xb, nx);

    transpose_w4<<<dim3(D_MODEL / 32, D_MODEL / 32, 4), dim3(32, 8), 0, stream>>>(
        Wq, Wk, Wv, Wo, Wtq, Wtk, Wtv, Wto);

    gemm_qkv<<<dim3(D_MODEL / 128, MTOT / 128, 3), 256, 0, stream>>>(
        xb, Wtq, Wtk, Wtv, bq, bk, bv, Q, Kh, Vt);

    attn_kernel<<<dim3(SEQ / 128, BATCH * NHEAD, 2), 256, 0, stream>>>(
        Q, Kh, Vt, Opart, lpart);

    attn_combine<<<dim3(SEQ / 64, BATCH * NHEAD), 256, 0, stream>>>(Opart, lpart, A2);

    gemm_proj<<<dim3(D_MODEL / 128, MTOT / 64), 256, 0, stream>>>(A2, Wto, bo, out);
}

// Round 5
// 188.734 us; speedup vs baseline: 1.2562x; 1.2562x over previous
//
#include <hip/hip_runtime.h>
#include <hip/hip_bf16.h>

typedef __bf16 bf16_t;
typedef __bf16 bf16x8 __attribute__((ext_vector_type(8)));
typedef __bf16 bf16x4 __attribute__((ext_vector_type(4)));
typedef float floatx4 __attribute__((ext_vector_type(4)));
typedef short short4v __attribute__((ext_vector_type(4)));

#define D_MODEL 1024
#define SEQ     2048
#define BATCH   2
#define NHEAD   16
#define HDIM    64
#define MTOT    (BATCH * SEQ)   /* 4096 */

// 1/sqrt(64) * log2(e): exp2(s) == exp(s/8) with this folded into Q
#define QSCALE  0.18033688011112042f

union PBu { bf16x4 b; short4v s; };

__device__ __forceinline__ void async_copy16(const bf16_t* g, bf16_t* l) {
    __builtin_amdgcn_global_load_lds(
        (const __attribute__((address_space(1))) void*)g,
        (__attribute__((address_space(3))) void*)l, 16, 0, 0);
}

// ---------------- convert fp32 -> bf16 (x) ----------------
__global__ void cvt_f32_bf16(const float* __restrict__ x, bf16_t* __restrict__ y, int n) {
    int i = (blockIdx.x * 256 + threadIdx.x) * 4;
    if (i < n) {
        const float4 v = *(const float4*)(x + i);
        bf16x4 o = { (bf16_t)v.x, (bf16_t)v.y, (bf16_t)v.z, (bf16_t)v.w };
        *(bf16x4*)(y + i) = o;
    }
}

// ---------------- transpose 4x W [K,N] f32 -> Wt [N,K] bf16 ----------------
__global__ void transpose_w4(
    const float* __restrict__ W0, const float* __restrict__ W1,
    const float* __restrict__ W2, const float* __restrict__ W3,
    bf16_t* __restrict__ T0, bf16_t* __restrict__ T1,
    bf16_t* __restrict__ T2, bf16_t* __restrict__ T3)
{
    __shared__ float tile[32][33];
    const int z = blockIdx.z;
    const float* W = (z == 0) ? W0 : (z == 1) ? W1 : (z == 2) ? W2 : W3;
    bf16_t*     Wt = (z == 0) ? T0 : (z == 1) ? T1 : (z == 2) ? T2 : T3;
    const int tx = threadIdx.x, ty = threadIdx.y;
    const int k0 = blockIdx.y * 32, n0 = blockIdx.x * 32;
#pragma unroll
    for (int j = 0; j < 32; j += 8)
        tile[ty + j][tx] = W[(size_t)(k0 + ty + j) * D_MODEL + n0 + tx];
    __syncthreads();
#pragma unroll
    for (int j = 0; j < 32; j += 8)
        Wt[(size_t)(n0 + ty + j) * D_MODEL + k0 + tx] = (bf16_t)tile[tx][ty + j];
}

// ---------------- 128x128 GEMM mainloop (global_load_lds + XOR swizzle) ----------------
__device__ __forceinline__ void gemm_mainloop(
    const bf16_t* __restrict__ A, const bf16_t* __restrict__ Bt,
    int m0, int n0, bf16_t* As, bf16_t* Bs, floatx4 acc[4][4])
{
    const int tid  = threadIdx.x;
    const int lane = tid & 63;
    const int wid  = tid >> 6;
    const int quad = lane >> 4;
    const int col  = lane & 15;
    const int wm   = (wid >> 1) * 64;
    const int wn   = (wid & 1) * 64;
    const int srow = tid >> 3;                       // 0..31
    const int scc  = ((tid & 7) ^ (srow & 7)) * 8;   // swizzled source col chunk
    const int xorc = col & 7;

    const bf16_t* Ag = A  + (size_t)(m0 + srow) * D_MODEL + scc;
    const bf16_t* Bg = Bt + (size_t)(n0 + srow) * D_MODEL + scc;
    bf16_t* Al = As + tid * 8;
    bf16_t* Bl = Bs + tid * 8;

    for (int kb = 0; kb < D_MODEL; kb += 64) {
#pragma unroll
        for (int p = 0; p < 4; ++p) {
            async_copy16(Ag + kb + p * (32 * D_MODEL), Al + p * 2048);
            async_copy16(Bg + kb + p * (32 * D_MODEL), Bl + p * 2048);
        }
        __syncthreads();
#pragma unroll
        for (int kh = 0; kh < 2; ++kh) {
            bf16x8 af[4], bfr[4];
#pragma unroll
            for (int i = 0; i < 4; ++i)
                af[i] = *(const bf16x8*)(As + (wm + i * 16 + col) * 64 + (((kh * 4 + quad) ^ xorc) * 8));
#pragma unroll
            for (int j = 0; j < 4; ++j)
                bfr[j] = *(const bf16x8*)(Bs + (wn + j * 16 + col) * 64 + (((kh * 4 + quad) ^ xorc) * 8));
#pragma unroll
            for (int i = 0; i < 4; ++i)
#pragma unroll
                for (int j = 0; j < 4; ++j)
                    acc[i][j] = __builtin_amdgcn_mfma_f32_16x16x32_bf16(af[i], bfr[j], acc[i][j], 0, 0, 0);
        }
        __syncthreads();
    }
}

// ---------------- QKV GEMM: grid (8, 32, 3) ----------------
__global__ __launch_bounds__(256, 3) void gemm_qkv(
    const bf16_t* __restrict__ xb,
    const bf16_t* __restrict__ Wtq, const bf16_t* __restrict__ Wtk, const bf16_t* __restrict__ Wtv,
    const float* __restrict__ bq, const float* __restrict__ bk, const float* __restrict__ bv,
    bf16_t* __restrict__ Q, bf16_t* __restrict__ Kh, bf16_t* __restrict__ Vt)
{
    __shared__ bf16_t As[128 * 64];
    __shared__ bf16_t Bs[128 * 64];
    const int z = blockIdx.z;
    const bf16_t* Bt   = (z == 0) ? Wtq : (z == 1) ? Wtk : Wtv;
    const float*  bias = (z == 0) ? bq  : (z == 1) ? bk  : bv;
    bf16_t*       O    = (z == 0) ? Q   : (z == 1) ? Kh  : Vt;
    const float   qs   = (z == 0) ? QSCALE : 1.0f;
    const int m0 = blockIdx.y * 128;
    const int n0 = blockIdx.x * 128;

    floatx4 acc[4][4];
#pragma unroll
    for (int i = 0; i < 4; ++i)
#pragma unroll
        for (int j = 0; j < 4; ++j)
            acc[i][j] = (floatx4){0.f, 0.f, 0.f, 0.f};

    gemm_mainloop(xb, Bt, m0, n0, As, Bs, acc);

    const int tid  = threadIdx.x;
    const int lane = tid & 63;
    const int wid  = tid >> 6;
    const int quad = lane >> 4;
    const int col  = lane & 15;
    const int wm   = (wid >> 1) * 64;
    const int wn   = (wid & 1) * 64;

    if (z == 2) {
        // Vt[b,h,d,s]: 4 consecutive s per lane -> bf16x4 stores
#pragma unroll
        for (int i = 0; i < 4; ++i) {
#pragma unroll
            for (int j = 0; j < 4; ++j) {
                const int n = n0 + wn + j * 16 + col;
                const float bb = bias[n];
                const int mb = m0 + wm + i * 16 + quad * 4;
                const size_t bhb = (size_t)((mb >> 11) * NHEAD + (n >> 6)) * (SEQ * HDIM);
                bf16x4 pk = { (bf16_t)(acc[i][j][0] + bb), (bf16_t)(acc[i][j][1] + bb),
                              (bf16_t)(acc[i][j][2] + bb), (bf16_t)(acc[i][j][3] + bb) };
                *(bf16x4*)(O + bhb + (size_t)(n & 63) * SEQ + (mb & 2047)) = pk;
            }
        }
    } else {
#pragma unroll
        for (int i = 0; i < 4; ++i) {
#pragma unroll
            for (int j = 0; j < 4; ++j) {
                const int n = n0 + wn + j * 16 + col;
                const float bb = bias[n];
#pragma unroll
                for (int r = 0; r < 4; ++r) {
                    const int m = m0 + wm + i * 16 + quad * 4 + r;
                    const float v = (acc[i][j][r] + bb) * qs;
                    const size_t bhb = (size_t)((m >> 11) * NHEAD + (n >> 6)) * (SEQ * HDIM);
                    O[bhb + (size_t)(m & 2047) * HDIM + (n & 63)] = (bf16_t)v;
                }
            }
        }
    }
}

// ---------------- flash attention, S^T formulation, no K-split ----------------
// grid 1024 blocks (XCD-swizzled), 256 thr; wave owns 16 q rows; KT=64; writes A2 directly.
__global__ __launch_bounds__(256, 4) void attn_kernel(
    const bf16_t* __restrict__ Q, const bf16_t* __restrict__ K,
    const bf16_t* __restrict__ Vt, bf16_t* __restrict__ A2)
{
    __shared__ bf16_t Ks[64 * 64];   // [kk][d], swizzled (8 KB)
    __shared__ bf16_t Vs[64 * 64];   // [d][s_local], swizzled (8 KB)

    const int tid  = threadIdx.x;
    const int lane = tid & 63;
    const int wid  = tid >> 6;
    const int quad = lane >> 4;
    const int col  = lane & 15;
    const int xorc = col & 7;

    // XCD swizzle: dispatcher round-robins blocks over 8 XCDs (blk % 8).
    // Give each XCD 4 complete bh slices -> K/V/Q stay L2-resident (~3 MB/XCD).
    const int blk = blockIdx.x;          // 0..1023
    const int idx = blk >> 3;            // 0..127
    const int bh  = (blk & 7) * 4 + (idx >> 5);
    const int q0  = (idx & 31) * 64;
    const int b   = bh >> 4, h = bh & 15;

    const bf16_t* Qb = Q  + (size_t)bh * (SEQ * HDIM);
    const bf16_t* Kb = K  + (size_t)bh * (SEQ * HDIM);
    const bf16_t* Vb = Vt + (size_t)bh * (SEQ * HDIM);  // [d][s]

    // Q B-fragments (n=q=col, kk=d=quad*8+j); scale folded in
    const int qrow = q0 + wid * 16 + col;
    bf16x8 qf0 = *(const bf16x8*)(Qb + (size_t)qrow * HDIM + quad * 8);
    bf16x8 qf1 = *(const bf16x8*)(Qb + (size_t)qrow * HDIM + 32 + quad * 8);

    floatx4 o_acc[4];   // O^T: lane holds (d = dt*16+quad*4+r, q = col)
    float lsum = 0.f;
#pragma unroll
    for (int dt = 0; dt < 4; ++dt)
        o_acc[dt] = (floatx4){0.f, 0.f, 0.f, 0.f};

    // staging maps (async copy: LDS dest = tid*16B per 4KB chunk)
    const int srow = tid >> 3;                          // 0..31
    const int scc  = ((tid & 7) ^ (srow & 7)) * 8;
    const bf16_t* Kg = Kb + (size_t)srow * HDIM + scc;
    const bf16_t* Vg = Vb + (size_t)srow * SEQ + scc;
    bf16_t* KsL = Ks + tid * 8;
    bf16_t* VsL = Vs + tid * 8;

    for (int it = 0; it < 32; ++it) {
        const int ko = it * 64;
        async_copy16(Kg + (size_t)ko * HDIM, KsL);
        async_copy16(Kg + (size_t)(ko + 32) * HDIM, KsL + 2048);
        async_copy16(Vg + ko, VsL);
        async_copy16(Vg + (size_t)32 * SEQ + ko, VsL + 2048);
        __syncthreads();

        // K fragments (A-operand of S^T): m = k = t*16+col, kk = d
        bf16x8 kf[4][2];
#pragma unroll
        for (int t = 0; t < 4; ++t) {
            kf[t][0] = *(const bf16x8*)(Ks + (t * 16 + col) * 64 + ((quad ^ xorc) * 8));
            kf[t][1] = *(const bf16x8*)(Ks + (t * 16 + col) * 64 + (((4 + quad) ^ xorc) * 8));
        }
        // V^T fragments (A-operand of PV, K=16): m = d = dt*16+col, k = t*16+quad*4+j
        short4v vfr[4][4];
#pragma unroll
        for (int dt = 0; dt < 4; ++dt)
#pragma unroll
            for (int t = 0; t < 4; ++t) {
                const int sch = t * 2 + (quad >> 1);
                vfr[dt][t] = *(const short4v*)(Vs + (dt * 16 + col) * 64 + ((sch ^ xorc) * 8) + (quad & 1) * 4);
            }

        floatx4 s_acc[4];
        short4v pb[4];
#pragma unroll
        for (int t = 0; t < 4; ++t) {
            s_acc[t] = (floatx4){0.f, 0.f, 0.f, 0.f};
            s_acc[t] = __builtin_amdgcn_mfma_f32_16x16x32_bf16(kf[t][0], qf0, s_acc[t], 0, 0, 0);
            s_acc[t] = __builtin_amdgcn_mfma_f32_16x16x32_bf16(kf[t][1], qf1, s_acc[t], 0, 0, 0);
        }
#pragma unroll
        for (int t = 0; t < 4; ++t) {
            const float p0 = __builtin_amdgcn_exp2f(s_acc[t][0]);
            const float p1 = __builtin_amdgcn_exp2f(s_acc[t][1]);
            const float p2 = __builtin_amdgcn_exp2f(s_acc[t][2]);
            const float p3 = __builtin_amdgcn_exp2f(s_acc[t][3]);
            lsum += (p0 + p1) + (p2 + p3);
            PBu u;
            u.b = (bf16x4){ (bf16_t)p0, (bf16_t)p1, (bf16_t)p2, (bf16_t)p3 };
            pb[t] = u.s;
        }
#pragma unroll
        for (int dt = 0; dt < 4; ++dt)
#pragma unroll
            for (int t = 0; t < 4; ++t)
                o_acc[dt] = __builtin_amdgcn_mfma_f32_16x16x16bf16_1k(vfr[dt][t], pb[t], o_acc[dt], 0, 0, 0);
        __syncthreads();
    }

    // l: lanes hold disjoint k-partials (by quad); reduce across quads
    lsum += __shfl_xor(lsum, 16, 64);
    lsum += __shfl_xor(lsum, 32, 64);
    const float inv = 1.0f / lsum;

    // epilogue: A2[b, q, h*64+d] bf16, 8B per lane per dt
    bf16_t* dst = A2 + ((size_t)(b * SEQ + qrow)) * D_MODEL + h * HDIM + quad * 4;
#pragma unroll
    for (int dt = 0; dt < 4; ++dt) {
        bf16x4 pk = { (bf16_t)(o_acc[dt][0] * inv), (bf16_t)(o_acc[dt][1] * inv),
                      (bf16_t)(o_acc[dt][2] * inv), (bf16_t)(o_acc[dt][3] * inv) };
        *(bf16x4*)(dst + dt * 16) = pk;
    }
}

// ---------------- output projection: 64x128 tiles, grid (8, 64) ----------------
__global__ __launch_bounds__(256, 3) void gemm_proj(
    const bf16_t* __restrict__ A2, const bf16_t* __restrict__ Wto,
    const float* __restrict__ bo, float* __restrict__ out)
{
    __shared__ bf16_t As[64 * 64];    // 8 KB
    __shared__ bf16_t Bs[128 * 64];   // 16 KB
    const int m0 = blockIdx.y * 64;
    const int n0 = blockIdx.x * 128;

    const int tid  = threadIdx.x;
    const int lane = tid & 63;
    const int wid  = tid >> 6;
    const int quad = lane >> 4;
    const int col  = lane & 15;
    const int wm   = (wid >> 1) * 32;
    const int wn   = (wid & 1) * 64;
    const int srow = tid >> 3;
    const int scc  = ((tid & 7) ^ (srow & 7)) * 8;
    const int xorc = col & 7;

    floatx4 acc[2][4];
#pragma unroll
    for (int i = 0; i < 2; ++i)
#pragma unroll
        for (int j = 0; j < 4; ++j)
            acc[i][j] = (floatx4){0.f, 0.f, 0.f, 0.f};

    const bf16_t* Ag = A2  + (size_t)(m0 + srow) * D_MODEL + scc;
    const bf16_t* Bg = Wto + (size_t)(n0 + srow) * D_MODEL + scc;
    bf16_t* Al = As + tid * 8;
    bf16_t* Bl = Bs + tid * 8;

    for (int kb = 0; kb < D_MODEL; kb += 64) {
#pragma unroll
        for (int p = 0; p < 2; ++p)
            async_copy16(Ag + kb + p * (32 * D_MODEL), Al + p * 2048);
#pragma unroll
        for (int p = 0; p < 4; ++p)
            async_copy16(Bg + kb + p * (32 * D_MODEL), Bl + p * 2048);
        __syncthreads();
#pragma unroll
        for (int kh = 0; kh < 2; ++kh) {
            bf16x8 af[2], bfr[4];
#pragma unroll
            for (int i = 0; i < 2; ++i)
                af[i] = *(const bf16x8*)(As + (wm + i * 16 + col) * 64 + (((kh * 4 + quad) ^ xorc) * 8));
#pragma unroll
            for (int j = 0; j < 4; ++j)
                bfr[j] = *(const bf16x8*)(Bs + (wn + j * 16 + col) * 64 + (((kh * 4 + quad) ^ xorc) * 8));
#pragma unroll
            for (int i = 0; i < 2; ++i)
#pragma unroll
                for (int j = 0; j < 4; ++j)
                    acc[i][j] = __builtin_amdgcn_mfma_f32_16x16x32_bf16(af[i], bfr[j], acc[i][j], 0, 0, 0);
        }
        __syncthreads();
    }

#pragma unroll
    for (int i = 0; i < 2; ++i) {
#pragma unroll
        for (int j = 0; j < 4; ++j) {
            const int n = n0 + wn + j * 16 + col;
            const float bb = bo[n];
#pragma unroll
            for (int r = 0; r < 4; ++r) {
                const int m = m0 + wm + i * 16 + quad * 4 + r;
                out[(size_t)m * D_MODEL + n] = acc[i][j][r] + bb;
            }
        }
    }
}

// ---------------- host ----------------
extern "C" void kernel_launch(void* const* d_in, const int* in_sizes, int n_in,
                              void* d_out, int out_size, void* d_ws, size_t ws_size,
                              hipStream_t stream) {
    const float* x  = (const float*)d_in[0];
    const float* Wq = (const float*)d_in[1];
    const float* bq = (const float*)d_in[2];
    const float* Wk = (const float*)d_in[3];
    const float* bk = (const float*)d_in[4];
    const float* Wv = (const float*)d_in[5];
    const float* bv = (const float*)d_in[6];
    const float* Wo = (const float*)d_in[7];
    const float* bo = (const float*)d_in[8];
    float* out = (float*)d_out;

    const size_t MB = 1ull << 20;
    char* ws = (char*)d_ws;
    bf16_t* Q     = (bf16_t*)(ws + 0 * MB);    // 8 MB  [b,h,s,d]
    bf16_t* Kh    = (bf16_t*)(ws + 8 * MB);    // 8 MB  [b,h,s,d]
    bf16_t* Vt    = (bf16_t*)(ws + 16 * MB);   // 8 MB  [b,h,d,s]
    bf16_t* A2    = (bf16_t*)(ws + 24 * MB);   // 8 MB  [b,s,h*d]
    bf16_t* xb    = (bf16_t*)(ws + 32 * MB);   // 8 MB
    bf16_t* Wtq   = (bf16_t*)(ws + 40 * MB);   // 2 MB each
    bf16_t* Wtk   = (bf16_t*)(ws + 42 * MB);
    bf16_t* Wtv   = (bf16_t*)(ws + 44 * MB);
    bf16_t* Wto   = (bf16_t*)(ws + 46 * MB);

    const int nx = MTOT * D_MODEL;
    cvt_f32_bf16<<<nx / (256 * 4), 256, 0, stream>>>(x, xb, nx);

    transpose_w4<<<dim3(D_MODEL / 32, D_MODEL / 32, 4), dim3(32, 8), 0, stream>>>(
        Wq, Wk, Wv, Wo, Wtq, Wtk, Wtv, Wto);

    gemm_qkv<<<dim3(D_MODEL / 128, MTOT / 128, 3), 256, 0, stream>>>(
        xb, Wtq, Wtk, Wtv, bq, bk, bv, Q, Kh, Vt);

    attn_kernel<<<dim3(1024), 256, 0, stream>>>(Q, Kh, Vt, A2);

    gemm_proj<<<dim3(D_MODEL / 128, MTOT / 64), 256, 0, stream>>>(A2, Wto, bo, out);
}